// Round 10
// baseline (116.343 us; speedup 1.0000x reference)
//
#include <hip/hip_runtime.h>
#include <hip/hip_bf16.h>
#include <stdint.h>

using f32x4  = __attribute__((ext_vector_type(4))) float;
using bf16x8 = __attribute__((ext_vector_type(8))) __bf16;
using bf16x4 = __attribute__((ext_vector_type(4))) __bf16;
using bf16x2 = __attribute__((ext_vector_type(2))) __bf16;
typedef unsigned int u32;

#define SEQ 4096

// D[q 4g+r][d c] += A[q c][k 4g+e] * B[k 4g+e][d c]   (K=16 keys)
__device__ __forceinline__ void mfma16(f32x4& acc, bf16x4 a, bf16x4 b) {
    asm volatile("v_mfma_f32_16x16x16_bf16 %0, %1, %2, %0"
                 : "+v"(acc) : "v"(a), "v"(b));
}

__global__ __launch_bounds__(1024, 4) void lattn_kern(
        const float* __restrict__ Q, const float* __restrict__ K,
        const float* __restrict__ V, float* __restrict__ O)
{
    // K ring: [512 rows][64 dims] bf16, 16B-granule ^= (row&7)      (65536 B)
    __shared__ __bf16 Kl[512 * 64];
    // V^T ring: [64 dims][520 cols] bf16, row stride 1040 B          (66560 B)
    __shared__ __bf16 Vt[64 * 520];

    const int tid  = threadIdx.x;
    const int wv   = tid >> 6;     // 0..15
    const int lane = tid & 63;
    const int g    = lane >> 4;
    const int c    = lane & 15;
    const u32 swc  = (u32)(c & 7);

    const int b   = blockIdx.x >> 2;    // head
    const int qt  = blockIdx.x & 3;     // head-quarter
    const int t00 = qt * 1024;
    const size_t baseB = (size_t)b * (SEQ * 64);

    int r0 = 384;   // ring row of window start; (t00-128) mod 512 = 384 always

    // ---------------- prologue: stage 512-key window ----------------
    #pragma unroll
    for (int it = 0; it < 4; ++it) {
        const int ch = tid + it * 1024;
        const int row = ch >> 3, dg = ch & 7;
        const int grow = (t00 - 128 + row) & (SEQ - 1);
        const int rr   = (384 + row) & 511;
        const float* src = K + baseB + (size_t)grow * 64 + dg * 8;
        f32x4 k0 = *(const f32x4*)src, k1 = *(const f32x4*)(src + 4);
        bf16x8 hk;
        #pragma unroll
        for (int u = 0; u < 4; ++u) { hk[u] = (__bf16)k0[u]; hk[u + 4] = (__bf16)k1[u]; }
        *(bf16x8*)((char*)Kl + rr * 128 + (((u32)dg ^ (u32)(rr & 7)) << 4)) = hk;
    }
    #pragma unroll
    for (int it = 0; it < 2; ++it) {
        const int ch = tid + it * 1024;
        const int rp = ch >> 3, dg = ch & 7;
        const int grow = (t00 - 128 + 2 * rp) & (SEQ - 1);   // even: pair contiguous
        const int col  = (384 + 2 * rp) & 511;
        const float* src = V + baseB + (size_t)grow * 64 + dg * 8;
        f32x4 a0 = *(const f32x4*)src,        a1 = *(const f32x4*)(src + 4);
        f32x4 b0 = *(const f32x4*)(src + 64), b1 = *(const f32x4*)(src + 68);
        #pragma unroll
        for (int u = 0; u < 8; ++u) {
            const int d = dg * 8 + u;
            bf16x2 pv;
            pv[0] = (__bf16)((u < 4) ? a0[u] : a1[u - 4]);
            pv[1] = (__bf16)((u < 4) ? b0[u] : b1[u - 4]);
            *(bf16x2*)((char*)Vt + (u32)d * 1040u + (u32)col * 2u) = pv;
        }
    }

    // ---------------- prologue: Q frags for tile 0 ----------------
    bf16x8 aq0, aq1;
    {
        const float* qp = Q + baseB + (size_t)(t00 + wv * 16 + c) * 64 + g * 8;
        f32x4 q0 = *(const f32x4*)qp,        q1 = *(const f32x4*)(qp + 4);
        f32x4 q2 = *(const f32x4*)(qp + 32), q3 = *(const f32x4*)(qp + 36);
        #pragma unroll
        for (int u = 0; u < 4; ++u) {
            aq0[u] = (__bf16)q0[u]; aq0[u + 4] = (__bf16)q1[u];
            aq1[u] = (__bf16)q2[u]; aq1[u + 4] = (__bf16)q3[u];
        }
    }

    for (int i = 0; i < 4; ++i) {
        const int t0 = t00 + i * 256;
        __syncthreads();                       // B_a: window (and deltas) visible

        // ---- S^T = K Q^T : 17 tiles, lane holds [key 4g+r][query c] ----
        f32x4 s_[17];
        const int rb = r0 + 16 * wv + c;
        __builtin_amdgcn_s_setprio(1);
        #pragma unroll
        for (int lt = 0; lt < 17; ++lt) {
            const int row = (rb + 16 * lt) & 511;      // row&7 == c&7
            const char* ka = (const char*)Kl + (u32)row * 128u;
            bf16x8 a0 = *(const bf16x8*)(ka + (((u32)g ^ swc) << 4));
            bf16x8 a1 = *(const bf16x8*)(ka + (((u32)(g + 4) ^ swc) << 4));
            f32x4 acc = {0.f, 0.f, 0.f, 0.f};
            acc = __builtin_amdgcn_mfma_f32_16x16x32_bf16(a0, aq0, acc, 0, 0, 0);
            acc = __builtin_amdgcn_mfma_f32_16x16x32_bf16(a1, aq1, acc, 0, 0, 0);
            s_[lt] = acc;
        }
        __builtin_amdgcn_s_setprio(0);

        // ---- early-issue next tile's Q (hidden under softmax+PV) ----
        f32x4 qn0, qn1, qn2, qn3;
        if (i < 3) {
            const float* qp = Q + baseB + (size_t)(t0 + 256 + wv * 16 + c) * 64 + g * 8;
            qn0 = *(const f32x4*)qp;        qn1 = *(const f32x4*)(qp + 4);
            qn2 = *(const f32x4*)(qp + 32); qn3 = *(const f32x4*)(qp + 36);
        }

        // ---- softmax over keys of query 16wv+c (no max-subtract) ----
        const int k4 = 4 * g;
        float sum = 0.f;
        #pragma unroll
        for (int lt = 0; lt < 17; ++lt) {
            #pragma unroll
            for (int r = 0; r < 4; ++r) {
                float e = exp2f(s_[lt][r] * 0.18033688f);   // 0.125*log2(e)
                if (lt == 0)  e = (k4 + r <  c) ? 0.f : e;
                if (lt == 16) e = (k4 + r >= c) ? 0.f : e;
                s_[lt][r] = e; sum += e;
            }
        }
        sum += __shfl_xor(sum, 16, 64);
        sum += __shfl_xor(sum, 32, 64);
        const float inv = 1.0f / sum;

        // ---- P -> normalized bf16 A-frags (s_ dies here, freeing VGPRs) ----
        bf16x4 pa[17];
        #pragma unroll
        for (int lt = 0; lt < 17; ++lt) {
            #pragma unroll
            for (int r = 0; r < 4; ++r) pa[lt][r] = (__bf16)(s_[lt][r] * inv);
        }

        // ---- early-issue next window's 256-row K/V delta (T14) ----
        f32x4 dk0a, dk0b, dk1a, dk1b, dv[4];
        int krow0 = 0, krow1 = 0, vcol = 0;
        const int kdg = tid & 7;
        if (i < 3) {
            {
                const int row = tid >> 3;                  // 0..127
                const int grow = (t0 + 384 + row) & (SEQ - 1);
                const float* s0 = K + baseB + (size_t)grow * 64 + kdg * 8;
                dk0a = *(const f32x4*)s0; dk0b = *(const f32x4*)(s0 + 4);
                krow0 = (r0 + row) & 511;
                const int grow1 = (t0 + 384 + row + 128) & (SEQ - 1);
                const float* s1 = K + baseB + (size_t)grow1 * 64 + kdg * 8;
                dk1a = *(const f32x4*)s1; dk1b = *(const f32x4*)(s1 + 4);
                krow1 = (r0 + row + 128) & 511;
            }
            {
                const int rp = tid >> 3;                   // 0..127
                const int grow = (t0 + 384 + 2 * rp) & (SEQ - 1);
                const float* s0 = V + baseB + (size_t)grow * 64 + kdg * 8;
                dv[0] = *(const f32x4*)s0;        dv[1] = *(const f32x4*)(s0 + 4);
                dv[2] = *(const f32x4*)(s0 + 64); dv[3] = *(const f32x4*)(s0 + 68);
                vcol = (r0 + 2 * rp) & 511;
            }
        }

        // ---- O = P V ----
        f32x4 o[4] = {{0,0,0,0},{0,0,0,0},{0,0,0,0},{0,0,0,0}};
        const int cb = r0 + 16 * wv + 4 * g;
        __builtin_amdgcn_s_setprio(1);
        #pragma unroll
        for (int lt = 0; lt < 17; ++lt) {
            const int col = (cb + 16 * lt) & 511;          // mult of 4, no pair-wrap
            #pragma unroll
            for (int dt = 0; dt < 4; ++dt) {
                const int d = dt * 16 + c;
                const bf16x4 vbf = *(const bf16x4*)((const char*)Vt
                                    + (u32)d * 1040u + (u32)col * 2u);
                mfma16(o[dt], pa[lt], vbf);
            }
        }
        __builtin_amdgcn_s_setprio(0);
        asm volatile("s_nop 7\n\ts_nop 7" ::);   // MFMA(asm)->VMEM hazard guard

        // ---- store O ----
        #pragma unroll
        for (int dt = 0; dt < 4; ++dt) {
            #pragma unroll
            for (int r = 0; r < 4; ++r) {
                const int row = t0 + wv * 16 + 4 * g + r;
                O[baseB + (size_t)row * 64 + dt * 16 + c] = o[dt][r];
            }
        }

        // ---- ring update: write deltas into dead rows, roll Q frags ----
        if (i < 3) {
            __syncthreads();                   // B_c: all ring reads done
            bf16x8 hk;
            #pragma unroll
            for (int u = 0; u < 4; ++u) { hk[u] = (__bf16)dk0a[u]; hk[u + 4] = (__bf16)dk0b[u]; }
            *(bf16x8*)((char*)Kl + krow0 * 128 + (((u32)kdg ^ (u32)(krow0 & 7)) << 4)) = hk;
            #pragma unroll
            for (int u = 0; u < 4; ++u) { hk[u] = (__bf16)dk1a[u]; hk[u + 4] = (__bf16)dk1b[u]; }
            *(bf16x8*)((char*)Kl + krow1 * 128 + (((u32)kdg ^ (u32)(krow1 & 7)) << 4)) = hk;
            #pragma unroll
            for (int u = 0; u < 8; ++u) {
                const int d = kdg * 8 + u;
                bf16x2 pv;
                pv[0] = (__bf16)((u < 4) ? dv[0][u] : dv[1][u - 4]);
                pv[1] = (__bf16)((u < 4) ? dv[2][u] : dv[3][u - 4]);
                *(bf16x2*)((char*)Vt + (u32)d * 1040u + (u32)vcol * 2u) = pv;
            }
            r0 = (r0 + 256) & 511;
            #pragma unroll
            for (int u = 0; u < 4; ++u) {
                aq0[u] = (__bf16)qn0[u]; aq0[u + 4] = (__bf16)qn1[u];
                aq1[u] = (__bf16)qn2[u]; aq1[u + 4] = (__bf16)qn3[u];
            }
        }
    }
}

extern "C" void kernel_launch(void* const* d_in, const int* in_sizes, int n_in,
                              void* d_out, int out_size, void* d_ws, size_t ws_size,
                              hipStream_t stream) {
    const float* q = (const float*)d_in[0];
    const float* k = (const float*)d_in[1];
    const float* v = (const float*)d_in[2];
    float* o = (float*)d_out;
    const int nB = in_sizes[0] / (SEQ * 64);   // 64
    dim3 grid(nB * 4), block(1024);
    hipLaunchKernelGGL(lattn_kern, grid, block, 0, stream, q, k, v, o);
}

// Round 12
// 71.742 us; speedup vs baseline: 1.6217x; 1.6217x over previous
//
#include <hip/hip_runtime.h>
#include <hip/hip_bf16.h>
#include <stdint.h>

using f32x4  = __attribute__((ext_vector_type(4))) float;
using bf16x8 = __attribute__((ext_vector_type(8))) __bf16;
using bf16x4 = __attribute__((ext_vector_type(4))) __bf16;
using bf16x2 = __attribute__((ext_vector_type(2))) __bf16;
typedef unsigned int u32;

#define SEQ 4096

// D[q 4g+r][d c] += A[q c][k 4g+e] * B[k 4g+e][d c]   (K=16 keys)
__device__ __forceinline__ void mfma16(f32x4& acc, bf16x4 a, bf16x4 b) {
    asm volatile("v_mfma_f32_16x16x16_bf16 %0, %1, %2, %0"
                 : "+v"(acc) : "v"(a), "v"(b));
}

__global__ __launch_bounds__(256, 2) void lattn_kern(
        const float* __restrict__ Q, const float* __restrict__ K,
        const float* __restrict__ V, float* __restrict__ O)
{
    // K ring: [320 rows][64 dims] bf16, 16B-granule ^= (row&7)            (40960 B)
    __shared__ __bf16 Kl[320 * 64];
    // V^T ring: [64 dims][320 key-cols] bf16, granule ^= (d&7)^((d>>3)&7) (40960 B)
    __shared__ __bf16 Vt[64 * 320];

    const int tid  = threadIdx.x;
    const int wv   = tid >> 6;
    const int lane = tid & 63;
    const int g    = lane >> 4;
    const int c    = lane & 15;
    const u32 swc  = (u32)(c & 7);

    const int b    = blockIdx.x >> 3;
    const int oct  = blockIdx.x & 7;
    const size_t baseB = (size_t)b * (SEQ * 64);
    const int t00  = oct * 512;

    int r0 = (t00 + SEQ - 128) % 320;

    // ---------------- prologue: stage full 320-key window ----------------
    #pragma unroll
    for (int it = 0; it < 10; ++it) {
        const int ch = tid + it * 256;
        const int j = ch >> 3, dg = ch & 7;
        const int grow = (t00 - 128 + j) & (SEQ - 1);
        int row = r0 + j; if (row >= 320) row -= 320;
        const float* src = K + baseB + (size_t)grow * 64 + dg * 8;
        f32x4 k0 = *(const f32x4*)src, k1 = *(const f32x4*)(src + 4);
        bf16x8 hk;
        #pragma unroll
        for (int u = 0; u < 4; ++u) { hk[u] = (__bf16)k0[u]; hk[u + 4] = (__bf16)k1[u]; }
        *(bf16x8*)((char*)Kl + row * 128 + (((u32)dg ^ (u32)(row & 7)) << 4)) = hk;
    }
    #pragma unroll
    for (int it = 0; it < 5; ++it) {
        const int ch = tid + it * 256;
        const int rp = ch >> 3, dg = ch & 7;
        const int grow = (t00 - 128 + 2 * rp) & (SEQ - 1);
        int col = r0 + 2 * rp; if (col >= 320) col -= 320;
        const float* src = V + baseB + (size_t)grow * 64 + dg * 8;
        f32x4 a0 = *(const f32x4*)src,        a1 = *(const f32x4*)(src + 4);
        f32x4 b0 = *(const f32x4*)(src + 64), b1 = *(const f32x4*)(src + 68);
        #pragma unroll
        for (int u = 0; u < 8; ++u) {
            const int d = dg * 8 + u;
            bf16x2 pv;
            pv[0] = (__bf16)((u < 4) ? a0[u] : a1[u - 4]);
            pv[1] = (__bf16)((u < 4) ? b0[u] : b1[u - 4]);
            const u32 sw = (u32)(u ^ dg);
            *(bf16x2*)((char*)Vt + (((u32)d * 640u + (u32)col * 2u) ^ (sw << 4))) = pv;
        }
    }

    // ---------------- prologue: Q frags for tile 0 ----------------
    bf16x8 aq0, aq1;
    {
        const float* qp = Q + baseB + (size_t)(t00 + wv * 16 + c) * 64 + g * 8;
        f32x4 q0 = *(const f32x4*)qp,        q1 = *(const f32x4*)(qp + 4);
        f32x4 q2 = *(const f32x4*)(qp + 32), q3 = *(const f32x4*)(qp + 36);
        #pragma unroll
        for (int u = 0; u < 4; ++u) {
            aq0[u] = (__bf16)q0[u]; aq0[u + 4] = (__bf16)q1[u];
            aq1[u] = (__bf16)q2[u]; aq1[u + 4] = (__bf16)q3[u];
        }
    }

    for (int i = 0; i < 8; ++i) {
        const int t0 = t00 + i * 64;
        __syncthreads();                       // B_a: staged window visible

        // ---- fused S^T = K Q^T + exp + partial sum (17 tiles) ----
        // lane holds S^T[key 4g+r][query c]; e = exp(s/8), edge-masked
        f32x4 s_[17];
        const int rb = r0 + 16 * wv + c;
        const int k4 = 4 * g;
        float sum = 0.f;
        __builtin_amdgcn_s_setprio(1);
        #pragma unroll
        for (int lt = 0; lt < 17; ++lt) {
            int row = rb + 16 * lt; if (row >= 320) row -= 320;
            const char* ka = (const char*)Kl + (u32)row * 128u;
            bf16x8 a0 = *(const bf16x8*)(ka + (((u32)g ^ swc) << 4));
            bf16x8 a1 = *(const bf16x8*)(ka + (((u32)(g + 4) ^ swc) << 4));
            f32x4 acc = {0.f, 0.f, 0.f, 0.f};
            acc = __builtin_amdgcn_mfma_f32_16x16x32_bf16(a0, aq0, acc, 0, 0, 0);
            acc = __builtin_amdgcn_mfma_f32_16x16x32_bf16(a1, aq1, acc, 0, 0, 0);
            #pragma unroll
            for (int r = 0; r < 4; ++r) {
                float e = exp2f(acc[r] * 0.18033688f);   // 0.125*log2(e)
                if (lt == 0)  e = (k4 + r <  c) ? 0.f : e;
                if (lt == 16) e = (k4 + r >= c) ? 0.f : e;
                s_[lt][r] = e; sum += e;
            }
        }
        __builtin_amdgcn_s_setprio(0);

        // ---- early-issue next tile's Q + K/V delta loads ----
        f32x4 qn0, qn1, qn2, qn3, dk0, dk1, dk2, dk3, dv0, dv1, dv2, dv3;
        int krow0 = 0, krow1 = 0, vcol = 0, kdg = 0, vdg = 0;
        if (i < 7) {
            const float* qp = Q + baseB + (size_t)(t0 + 64 + wv * 16 + c) * 64 + g * 8;
            qn0 = *(const f32x4*)qp;        qn1 = *(const f32x4*)(qp + 4);
            qn2 = *(const f32x4*)(qp + 32); qn3 = *(const f32x4*)(qp + 36);
            {
                const int jj = tid >> 3; kdg = tid & 7;
                const int grow0 = (t0 + 192 + jj) & (SEQ - 1);
                const float* s0 = K + baseB + (size_t)grow0 * 64 + kdg * 8;
                dk0 = *(const f32x4*)s0; dk1 = *(const f32x4*)(s0 + 4);
                krow0 = r0 + jj;
                const int grow1 = (t0 + 192 + jj + 32) & (SEQ - 1);
                const float* s1 = K + baseB + (size_t)grow1 * 64 + kdg * 8;
                dk2 = *(const f32x4*)s1; dk3 = *(const f32x4*)(s1 + 4);
                krow1 = r0 + jj + 32;
            }
            {
                const int rp = tid >> 3; vdg = tid & 7;
                const int grow = (t0 + 192 + 2 * rp) & (SEQ - 1);
                const float* s0 = V + baseB + (size_t)grow * 64 + vdg * 8;
                dv0 = *(const f32x4*)s0;        dv1 = *(const f32x4*)(s0 + 4);
                dv2 = *(const f32x4*)(s0 + 64); dv3 = *(const f32x4*)(s0 + 68);
                vcol = r0 + 2 * rp;
            }
        }

        // ---- complete the row sum, normalize ----
        sum += __shfl_xor(sum, 16, 64);
        sum += __shfl_xor(sum, 32, 64);
        const float inv = 1.0f / sum;

        // ---- P -> normalized bf16 A-frags, in-register ----
        bf16x4 pa[17];
        #pragma unroll
        for (int lt = 0; lt < 17; ++lt) {
            #pragma unroll
            for (int r = 0; r < 4; ++r) pa[lt][r] = (__bf16)(s_[lt][r] * inv);
        }

        // ---- O = P V ----
        f32x4 o[4] = {{0,0,0,0},{0,0,0,0},{0,0,0,0},{0,0,0,0}};
        const int cb = r0 + 16 * wv + 4 * g;
        __builtin_amdgcn_s_setprio(1);
        #pragma unroll
        for (int lt = 0; lt < 17; ++lt) {
            int col = cb + 16 * lt; if (col >= 320) col -= 320;
            #pragma unroll
            for (int dt = 0; dt < 4; ++dt) {
                const int d  = dt * 16 + c;
                const u32 sw = (u32)((d & 7) ^ ((d >> 3) & 7));
                const u32 vb = ((u32)d * 640u + (u32)col * 2u) ^ (sw << 4);
                const bf16x4 vbf = *(const bf16x4*)((const char*)Vt + vb);
                mfma16(o[dt], pa[lt], vbf);
            }
        }
        __builtin_amdgcn_s_setprio(0);
        asm volatile("s_nop 7\n\ts_nop 7" ::);   // MFMA(asm)->VMEM read hazard guard

        // ---- store O: lane (g,c) -> O[q 16wv+4g+r][d 16dt+c] ----
        #pragma unroll
        for (int dt = 0; dt < 4; ++dt) {
            #pragma unroll
            for (int r = 0; r < 4; ++r) {
                const int row = t0 + wv * 16 + 4 * g + r;
                O[baseB + (size_t)row * 64 + dt * 16 + c] = o[dt][r];
            }
        }

        // ---- ring update: write deltas into dead rows, roll Q frags ----
        if (i < 7) {
            __syncthreads();                   // B_c: all ring reads done
            bf16x8 hk;
            #pragma unroll
            for (int u = 0; u < 4; ++u) { hk[u] = (__bf16)dk0[u]; hk[u + 4] = (__bf16)dk1[u]; }
            *(bf16x8*)((char*)Kl + krow0 * 128 + (((u32)kdg ^ (u32)(krow0 & 7)) << 4)) = hk;
            #pragma unroll
            for (int u = 0; u < 4; ++u) { hk[u] = (__bf16)dk2[u]; hk[u + 4] = (__bf16)dk3[u]; }
            *(bf16x8*)((char*)Kl + krow1 * 128 + (((u32)kdg ^ (u32)(krow1 & 7)) << 4)) = hk;
            #pragma unroll
            for (int u = 0; u < 8; ++u) {
                const int d = vdg * 8 + u;
                bf16x2 pv;
                pv[0] = (__bf16)((u < 4) ? dv0[u] : dv1[u - 4]);
                pv[1] = (__bf16)((u < 4) ? dv2[u] : dv3[u - 4]);
                const u32 sw = (u32)(u ^ vdg);
                *(bf16x2*)((char*)Vt + (((u32)d * 640u + (u32)vcol * 2u) ^ (sw << 4))) = pv;
            }
            r0 += 64; if (r0 >= 320) r0 -= 320;
            #pragma unroll
            for (int u = 0; u < 4; ++u) {
                aq0[u] = (__bf16)qn0[u]; aq0[u + 4] = (__bf16)qn1[u];
                aq1[u] = (__bf16)qn2[u]; aq1[u + 4] = (__bf16)qn3[u];
            }
        }
    }
}

extern "C" void kernel_launch(void* const* d_in, const int* in_sizes, int n_in,
                              void* d_out, int out_size, void* d_ws, size_t ws_size,
                              hipStream_t stream) {
    const float* q = (const float*)d_in[0];
    const float* k = (const float*)d_in[1];
    const float* v = (const float*)d_in[2];
    float* o = (float*)d_out;
    const int nB = in_sizes[0] / (SEQ * 64);   // 64
    dim3 grid(nB * 8), block(256);
    hipLaunchKernelGGL(lattn_kern, grid, block, 0, stream, q, k, v, o);
}